// Round 19
// baseline (70.877 us; speedup 1.0000x reference)
//
#include <hip/hip_runtime.h>
#include <cmath>

namespace {

typedef _Float16 h8 __attribute__((ext_vector_type(8)));
typedef _Float16 h2 __attribute__((ext_vector_type(2)));
typedef __fp16   fp2 __attribute__((ext_vector_type(2)));   // cvt_pkrtz native type

constexpr int C_     = 64;
constexpr int L_     = 32768;
constexpr int TILE   = 2048;
constexpr int HALO   = 776;           // receptive field 765, rounded to unit-8
constexpr int NB     = TILE + HALO;   // 2824 halfs
constexpr int NU     = NB / 8;        // 353 h8 units
constexpr int HALO_U = HALO / 8;      // 97
constexpr int NT     = L_ / TILE;     // 16 tiles per row
constexpr int BLK    = 64;            // ONE WAVE per block: __syncthreads is
                                      // just lgkmcnt(0); no s_barrier cost.
constexpr int UMAX   = 6;             // 6 unit-slots (slot5 partial: 33 lanes)

__device__ __forceinline__ h8 ld8(const _Float16* p) { return *reinterpret_cast<const h8*>(p); }
__device__ __forceinline__ void st8(_Float16* p, h8 v) { *reinterpret_cast<h8*>(p) = v; }
__device__ __forceinline__ float4 ld4f(const float* p) { return *reinterpret_cast<const float4*>(p); }
__device__ __forceinline__ void st4f(float* p, float4 v) { *reinterpret_cast<float4*>(p) = v; }
__device__ __forceinline__ h8 sp8(_Float16 v) { return (h8){v,v,v,v,v,v,v,v}; }

// Guaranteed v_pk_fma_f16 (r10: measured win vs mul/add trees).
__device__ __forceinline__ h8 fma8(h8 a, h8 b, h8 c) {
    return __builtin_elementwise_fma(a, b, c);
}

template<int K>
__device__ __forceinline__ h8 shconc(h8 A, h8 B) {
    return __builtin_shufflevector(A, B, K, K+1, K+2, K+3, K+4, K+5, K+6, K+7);
}

// f32x8 -> fp16x8 via v_cvt_pkrtz_f16_f32; absmax-verified (r12..r18).
__device__ __forceinline__ h2 pkrtz(float lo, float hi) {
    const fp2 r = __builtin_amdgcn_cvt_pkrtz(lo, hi);
    return __builtin_bit_cast(h2, r);
}
__device__ __forceinline__ h8 pack8(float4 a, float4 b) {
    const h2 p0 = pkrtz(a.x, a.y);
    const h2 p1 = pkrtz(a.z, a.w);
    const h2 p2 = pkrtz(b.x, b.y);
    const h2 p3 = pkrtz(b.z, b.w);
    return (h8){p0[0], p0[1], p1[0], p1[1], p2[0], p2[1], p3[0], p3[1]};
}

// tanh-form GELU: v * sigmoid(1.5958*v + 0.07135*v^3); absmax-verified vs erf
// across twelve rounds (identical 0.0078125 overall absmax).
__device__ __forceinline__ float gelu_f(float v) {
    const float z = v * (1.5957691216057308f + 0.0713548162726f * v * v);
    const float e = __expf(-z);
    return v * __builtin_amdgcn_rcpf(1.0f + e);
}

// 4-tap dot helpers (pure pk-FMA chains).
__device__ __forceinline__ h8 dot_nl(const h8 T0, const h8 T1, const h8 T2,
                                     const h8 T3, const _Float16* c) {
    h8 nl = sp8(c[0]) * T0;
    nl = fma8(sp8(c[1]), T1, nl);
    nl = fma8(sp8(c[2]), T2, nl);
    nl = fma8(sp8(c[3]), T3, nl);
    return nl;
}
__device__ __forceinline__ void dot_acc(const h8 T0, const h8 T1, const h8 T2,
                                        const h8 T3, const _Float16* c, h8& yv) {
    h8 yt = yv;
    yt = fma8(sp8(c[0]), T0, yt);
    yt = fma8(sp8(c[1]), T1, yt);
    yt = fma8(sp8(c[2]), T2, yt);
    yt = fma8(sp8(c[3]), T3, yt);
    yv = yt;
}

// One level, dilation D >= 2, SINGLE in-place LDS buffer, DESCENDING slots.
// Race-freedom (wave-lockstep): slot s only reads units of slots s-1 and s
// (taps reach <= 48 units down < 64); descending order means those units
// still hold level k-1 values; a slot's own write follows its reads in
// program order. One __syncthreads() per level = lgkmcnt(0) only (1 wave).
// Frontier recursion (correctness-proven r3..r18): STARTU per level
// 2,4,7,13,25,49,97; valid unit g at level D reads down to g-3D/8 >= prev
// STARTU (prev of D2 is the exact fused-staging l1, valid everywhere).
// Guards bound live ranges (r4-r7: unguarded -> 188 VGPR or demotion).
template<int D, int STARTU, bool LAST>
__device__ __forceinline__ void level_pass(_Float16* __restrict__ buf,
                                           const _Float16* h0h, const _Float16* h1h,
                                           _Float16 wih, _Float16 w0h,
                                           h8* lw, h8* yacc, int tid)
{
    _Float16 c1[4], c0[4];
#pragma unroll
    for (int t = 0; t < 4; ++t) {
        c1[t] = wih * h1h[t];
        c0[t] = LAST ? (_Float16)(w0h * h0h[t]) : h0h[t];
    }
#pragma unroll
    for (int uu = UMAX - 1; uu >= 0; --uu) {
        const int un = tid + uu * BLK;
        if (un >= STARTU && un < NU) {
            const int p = 8 * un;
            const h8 T3 = lw[uu];
            h8 T0, T1, T2;
            if constexpr (D == 2) {
                const h8 Lv = ld8(&buf[p - 8]);
                T0 = shconc<2>(Lv, T3); T1 = shconc<4>(Lv, T3); T2 = shconc<6>(Lv, T3);
            } else if constexpr (D == 4) {
                const h8 Lv = ld8(&buf[p - 8]);
                const h8 LL = ld8(&buf[p - 16]);
                T0 = shconc<4>(LL, Lv); T1 = Lv; T2 = shconc<4>(Lv, T3);
            } else {
                T0 = ld8(&buf[p - 3 * D]);
                T1 = ld8(&buf[p - 2 * D]);
                T2 = ld8(&buf[p - D]);
            }
            if (un >= HALO_U) dot_acc(T0, T1, T2, T3, c1, yacc[uu]);
            const h8 nl = dot_nl(T0, T1, T2, T3, c0);
            if constexpr (LAST) {
                yacc[uu] += nl;        // c0 pre-folded with w0
            } else {
                lw[uu] = nl;
                st8(&buf[p], nl);
            }
        }
    }
}

// (64,5): VGPR cap 102. 6-slot accumulators (12 h8 = 48) + tap transients
// ~ 70-90 live — under cap. LDS 5648B single buffer -> ~20+ resident
// independent waves/CU, ZERO inter-wave barriers.
__global__ __launch_bounds__(BLK, 5)
void cmrc_kernel(const float* __restrict__ x,
                 const float* __restrict__ h0,
                 const float* __restrict__ h1,
                 const float* __restrict__ w,
                 float* __restrict__ out)
{
    __shared__ alignas(16) _Float16 buf[NB];   // SINGLE in-place buffer, 5648 B

    const int tid  = threadIdx.x;
    const int blk  = blockIdx.x;
    const int tile = blk % NT;
    const int bc   = blk / NT;            // b*C + c
    const int c    = bc % C_;
    const long row = (long)bc * L_;
    const int  t0  = tile * TILE - HALO;  // global pos of buffer p=0

    // fp16 filter taps and level weights, converted ONCE.
    _Float16 h0h[4], h1h[4];
#pragma unroll
    for (int k = 0; k < 4; ++k) {
        h0h[k] = (_Float16)h0[c * 4 + k];
        h1h[k] = (_Float16)h1[c * 4 + k];
    }
    _Float16 wh[10];
#pragma unroll
    for (int i = 0; i < 10; ++i) wh[i] = (_Float16)w[c * 10 + i];

    // D=1 y-coefficients for the fused staging phase.
    _Float16 c18[4];
#pragma unroll
    for (int t = 0; t < 4; ++t) c18[t] = wh[8] * h1h[t];

    h8 lw[UMAX];     // running low residual (own units, registers)
    h8 yacc[UMAX];   // packed y accumulator

    // ---- Fused staging + D=1 level (taps from GLOBAL, exact everywhere) ----
    // Loads own 8 x-values plus the 8 preceding halfs (L1/L2-hit neighbor
    // data); computes l1 = conv(x,h0,1) in registers, y = w9*x +
    // w8*conv(x,h1,1), publishes ONLY l1 to LDS. Zero-fill left of t=0
    // matches the causal pad, so l1 is exact for every unit.
#pragma unroll
    for (int u = 0; u < UMAX; ++u) {
        yacc[u] = sp8((_Float16)0.f);
        const int un = tid + u * BLK;
        if (un < NU) {
            const int p = 8 * un;
            const int t = t0 + p;
            const float4 z4 = make_float4(0.f, 0.f, 0.f, 0.f);
            float4 xa = z4, xb = z4, xm1 = z4, xm2 = z4;
            if (t >= 0) { xa  = ld4f(&x[row + t]);      xb  = ld4f(&x[row + t + 4]); }
            if (t >= 8) { xm1 = ld4f(&x[row + t - 8]);  xm2 = ld4f(&x[row + t - 4]); }
            const h8 X0 = pack8(xa, xb);
            const h8 Xm = pack8(xm1, xm2);
            const h8 A0 = shconc<5>(Xm, X0);
            const h8 A1 = shconc<6>(Xm, X0);
            const h8 A2 = shconc<7>(Xm, X0);
            const h8 l1 = dot_nl(A0, A1, A2, X0, h0h);
            st8(&buf[p], l1);
            lw[u] = l1;
            if (un >= HALO_U) {
                h8 yv = sp8(wh[9]) * X0;
                dot_acc(A0, A1, A2, X0, c18, yv);
                yacc[u] = yv;
            }
        }
    }
    __syncthreads();   // 1-wave workgroup: lgkmcnt(0) only

    level_pass<2,   2,  false>(buf, h0h, h1h, wh[7], (_Float16)0.f, lw, yacc, tid); __syncthreads();
    level_pass<4,   4,  false>(buf, h0h, h1h, wh[6], (_Float16)0.f, lw, yacc, tid); __syncthreads();
    level_pass<8,   7,  false>(buf, h0h, h1h, wh[5], (_Float16)0.f, lw, yacc, tid); __syncthreads();
    level_pass<16,  13, false>(buf, h0h, h1h, wh[4], (_Float16)0.f, lw, yacc, tid); __syncthreads();
    level_pass<32,  25, false>(buf, h0h, h1h, wh[3], (_Float16)0.f, lw, yacc, tid); __syncthreads();
    level_pass<64,  49, false>(buf, h0h, h1h, wh[2], (_Float16)0.f, lw, yacc, tid); __syncthreads();
    level_pass<128, 97, true >(buf, h0h, h1h, wh[1], wh[0],         lw, yacc, tid);

    // ---- Epilogue: unpack to fp32, GELU, two float4 stores per unit ----
#pragma unroll
    for (int u = 0; u < UMAX; ++u) {
        const int un = tid + u * BLK;
        if (un >= HALO_U && un < NU) {
            const int p = 8 * un;
            const h8 v = yacc[u];
            float4 oa, ob;
            oa.x = gelu_f((float)v[0]); oa.y = gelu_f((float)v[1]);
            oa.z = gelu_f((float)v[2]); oa.w = gelu_f((float)v[3]);
            ob.x = gelu_f((float)v[4]); ob.y = gelu_f((float)v[5]);
            ob.z = gelu_f((float)v[6]); ob.w = gelu_f((float)v[7]);
            st4f(&out[row + t0 + p], oa);
            st4f(&out[row + t0 + p + 4], ob);
        }
    }
}

}  // namespace

extern "C" void kernel_launch(void* const* d_in, const int* in_sizes, int n_in,
                              void* d_out, int out_size, void* d_ws, size_t ws_size,
                              hipStream_t stream)
{
    const float* x  = (const float*)d_in[0];
    const float* h0 = (const float*)d_in[1];
    const float* h1 = (const float*)d_in[2];
    const float* w  = (const float*)d_in[3];
    float* out = (float*)d_out;

    const int nblocks = (out_size / L_) * NT;   // B*C*NT = 8192 one-wave blocks
    cmrc_kernel<<<nblocks, BLK, 0, stream>>>(x, h0, h1, w, out);
}

// Round 20
// 40.869 us; speedup vs baseline: 1.7342x; 1.7342x over previous
//
#include <hip/hip_runtime.h>
#include <cmath>

namespace {

typedef _Float16 h8 __attribute__((ext_vector_type(8)));
typedef _Float16 h2 __attribute__((ext_vector_type(2)));
typedef __fp16   fp2 __attribute__((ext_vector_type(2)));   // cvt_pkrtz native type

constexpr int C_     = 64;
constexpr int L_     = 32768;
constexpr int TILE   = 4096;
constexpr int HALO   = 776;           // receptive field 765, rounded to unit-8
constexpr int NB     = TILE + HALO;   // 4872 halfs
constexpr int NU     = NB / 8;        // 609 h8 units
constexpr int HALO_U = HALO / 8;      // 97
constexpr int NT     = L_ / TILE;     // 8 tiles per row
constexpr int BLK    = 256;
constexpr int S2N    = NU - 2 * BLK;  // 97: threads owning a third unit

__device__ __forceinline__ h8 ld8(const _Float16* p) { return *reinterpret_cast<const h8*>(p); }
__device__ __forceinline__ void st8(_Float16* p, h8 v) { *reinterpret_cast<h8*>(p) = v; }
__device__ __forceinline__ float4 ld4f(const float* p) { return *reinterpret_cast<const float4*>(p); }
__device__ __forceinline__ void st4f(float* p, float4 v) { *reinterpret_cast<float4*>(p) = v; }
__device__ __forceinline__ h8 sp8(_Float16 v) { return (h8){v,v,v,v,v,v,v,v}; }

// Guaranteed v_pk_fma_f16 (r10: measured win vs mul/add trees).
__device__ __forceinline__ h8 fma8(h8 a, h8 b, h8 c) {
    return __builtin_elementwise_fma(a, b, c);
}

template<int K>
__device__ __forceinline__ h8 shconc(h8 A, h8 B) {
    return __builtin_shufflevector(A, B, K, K+1, K+2, K+3, K+4, K+5, K+6, K+7);
}

// f32x8 -> fp16x8 via v_cvt_pkrtz_f16_f32; absmax-verified (r12..r18).
__device__ __forceinline__ h2 pkrtz(float lo, float hi) {
    const fp2 r = __builtin_amdgcn_cvt_pkrtz(lo, hi);
    return __builtin_bit_cast(h2, r);
}
__device__ __forceinline__ h8 pack8(float4 a, float4 b) {
    const h2 p0 = pkrtz(a.x, a.y);
    const h2 p1 = pkrtz(a.z, a.w);
    const h2 p2 = pkrtz(b.x, b.y);
    const h2 p3 = pkrtz(b.z, b.w);
    return (h8){p0[0], p0[1], p1[0], p1[1], p2[0], p2[1], p3[0], p3[1]};
}

// tanh-form GELU: v * sigmoid(1.5958*v + 0.07135*v^3); absmax-verified vs erf
// across thirteen rounds (identical 0.0078125 overall absmax).
__device__ __forceinline__ float gelu_f(float v) {
    const float z = v * (1.5957691216057308f + 0.0713548162726f * v * v);
    const float e = __expf(-z);
    return v * __builtin_amdgcn_rcpf(1.0f + e);
}

// 4-tap dot helpers (pure pk-FMA chains).
__device__ __forceinline__ h8 dot_nl(const h8 T0, const h8 T1, const h8 T2,
                                     const h8 T3, const _Float16* c) {
    h8 nl = sp8(c[0]) * T0;
    nl = fma8(sp8(c[1]), T1, nl);
    nl = fma8(sp8(c[2]), T2, nl);
    nl = fma8(sp8(c[3]), T3, nl);
    return nl;
}
__device__ __forceinline__ void dot_acc(const h8 T0, const h8 T1, const h8 T2,
                                        const h8 T3, const _Float16* c, h8& yv) {
    h8 yt = yv;
    yt = fma8(sp8(c[0]), T0, yt);
    yt = fma8(sp8(c[1]), T1, yt);
    yt = fma8(sp8(c[2]), T2, yt);
    yt = fma8(sp8(c[3]), T3, yt);
    yv = yt;
}

// Tap gather + two 4-tap dots + in-place publish for one unit of one level.
// D >= 2 only: D=1 is fused into the staging phase (taps from global).
template<int D, bool LAST>
__device__ __forceinline__ void unit_step(const _Float16* __restrict__ src,
                                          _Float16* __restrict__ dst, int un,
                                          h8& lwv, h8& yv, bool doY,
                                          const _Float16* c1, const _Float16* c0)
{
    const int p = 8 * un;
    const h8 T3 = lwv;
    h8 T0, T1, T2;
    if constexpr (D == 2) {
        const h8 Lv = ld8(&src[p - 8]);
        T0 = shconc<2>(Lv, T3); T1 = shconc<4>(Lv, T3); T2 = shconc<6>(Lv, T3);
    } else if constexpr (D == 4) {
        const h8 Lv = ld8(&src[p - 8]);
        const h8 LL = ld8(&src[p - 16]);
        T0 = shconc<4>(LL, Lv); T1 = Lv; T2 = shconc<4>(Lv, T3);
    } else {
        T0 = ld8(&src[p - 3 * D]);
        T1 = ld8(&src[p - 2 * D]);
        T2 = ld8(&src[p - D]);
    }
    if (doY) dot_acc(T0, T1, T2, T3, c1, yv);
    const h8 nl = dot_nl(T0, T1, T2, T3, c0);
    if constexpr (LAST) {
        yv += nl;                      // c0 pre-folded with w0
    } else {
        lwv = nl;
        st8(&dst[p], nl);
    }
}

// One level, dilation D >= 2. Slots compile-time specialized and ordered so
// the UNCONDITIONAL slot1 issues its ds_reads first:
//  slot1 (un=tid+256 in [256,512)): no guard (>=97 always, <NU, y always).
//  slot2 (un=tid+512): exists iff tid<S2N=97; y always.
//  slot0 (un=tid): guard tid>=STARTU; y iff tid>=HALO_U.
// Frontier recursion (correctness-proven r3..r18): STARTU per level
// 2,4,7,13,25,49,97; valid unit g at level D reads down to g-3D/8 >= prev
// STARTU (prev of D2 is the exact fused-staging l1, valid everywhere).
// Guards bound live ranges (r4-r7: unguarded -> 188 VGPR or demotion).
template<int D, int STARTU, bool LAST>
__device__ __forceinline__ void level_pass(const _Float16* __restrict__ src,
                                           _Float16* __restrict__ dst,
                                           const _Float16* h0h, const _Float16* h1h,
                                           _Float16 wih, _Float16 w0h,
                                           h8* lw, h8* yacc, int tid)
{
    _Float16 c1[4], c0[4];
#pragma unroll
    for (int t = 0; t < 4; ++t) {
        c1[t] = wih * h1h[t];
        c0[t] = LAST ? (_Float16)(w0h * h0h[t]) : h0h[t];
    }
    unit_step<D, LAST>(src, dst, tid + BLK, lw[1], yacc[1], true, c1, c0);
    if (tid < S2N)
        unit_step<D, LAST>(src, dst, tid + 2 * BLK, lw[2], yacc[2], true, c1, c0);
    if (tid >= STARTU)
        unit_step<D, LAST>(src, dst, tid, lw[0], yacc[0], tid >= HALO_U, c1, c0);
}

// min-waves=8 (VGPR cap 64): guarded structure measured 32 VGPR (r17) — ample.
// LDS 2x9744B -> 8 blocks/CU.
__global__ __launch_bounds__(BLK, 8)
void cmrc_kernel(const float* __restrict__ x,
                 const float* __restrict__ h0,
                 const float* __restrict__ h1,
                 const float* __restrict__ w,
                 float* __restrict__ out)
{
    __shared__ alignas(16) _Float16 buf[2][NB];

    const int tid  = threadIdx.x;
    const int blk  = blockIdx.x;
    const int tile = blk % NT;
    const int bc   = blk / NT;            // b*C + c
    const int c    = bc % C_;
    const long row = (long)bc * L_;
    const int  t0  = tile * TILE - HALO;  // global pos of buffer p=0

    // fp16 filter taps and level weights, converted ONCE.
    _Float16 h0h[4], h1h[4];
#pragma unroll
    for (int k = 0; k < 4; ++k) {
        h0h[k] = (_Float16)h0[c * 4 + k];
        h1h[k] = (_Float16)h1[c * 4 + k];
    }
    _Float16 wh[10];
#pragma unroll
    for (int i = 0; i < 10; ++i) wh[i] = (_Float16)w[c * 10 + i];

    // D=1 y-coefficients for the fused staging phase.
    _Float16 c18[4];
#pragma unroll
    for (int t = 0; t < 4; ++t) c18[t] = wh[8] * h1h[t];

    h8 lw[3];     // running low residual (own units, registers)
    h8 yacc[3];   // packed y accumulator

    // ---- Fused staging + D=1 level (taps from GLOBAL, exact everywhere) ----
    // Loads own 8 x-values plus the 8 preceding halfs (L2-hit neighbor data);
    // computes l1 = conv(x,h0,1) in registers, y = w9*x + w8*conv(x,h1,1),
    // publishes ONLY l1 to LDS. Zero-fill left of t=0 matches the causal pad,
    // so l1 is exact for every unit — no frontier constraint at this level.
#pragma unroll
    for (int u = 0; u < 3; ++u) {
        yacc[u] = sp8((_Float16)0.f);
        const int un = tid + u * BLK;
        if (un < NU) {
            const int p = 8 * un;
            const int t = t0 + p;
            float4 xa = make_float4(0.f, 0.f, 0.f, 0.f), xb = xa;
            float4 xm1 = xa, xm2 = xa;
            if (t >= 0) { xa = ld4f(&x[row + t]);     xb = ld4f(&x[row + t + 4]); }
            if (t >= 8) { xm1 = ld4f(&x[row + t - 8]); xm2 = ld4f(&x[row + t - 4]); }
            const h8 X0 = pack8(xa, xb);
            const h8 Xm = pack8(xm1, xm2);
            const h8 A0 = shconc<5>(Xm, X0);
            const h8 A1 = shconc<6>(Xm, X0);
            const h8 A2 = shconc<7>(Xm, X0);
            const h8 l1 = dot_nl(A0, A1, A2, X0, h0h);
            st8(&buf[0][p], l1);
            lw[u] = l1;
            if (un >= HALO_U) {
                h8 yv = sp8(wh[9]) * X0;
                dot_acc(A0, A1, A2, X0, c18, yv);
                yacc[u] = yv;
            }
        }
    }
    __syncthreads();

    level_pass<2,   2,  false>(buf[0], buf[1], h0h, h1h, wh[7], (_Float16)0.f, lw, yacc, tid); __syncthreads();
    level_pass<4,   4,  false>(buf[1], buf[0], h0h, h1h, wh[6], (_Float16)0.f, lw, yacc, tid); __syncthreads();
    level_pass<8,   7,  false>(buf[0], buf[1], h0h, h1h, wh[5], (_Float16)0.f, lw, yacc, tid); __syncthreads();
    level_pass<16,  13, false>(buf[1], buf[0], h0h, h1h, wh[4], (_Float16)0.f, lw, yacc, tid); __syncthreads();
    level_pass<32,  25, false>(buf[0], buf[1], h0h, h1h, wh[3], (_Float16)0.f, lw, yacc, tid); __syncthreads();
    level_pass<64,  49, false>(buf[1], buf[0], h0h, h1h, wh[2], (_Float16)0.f, lw, yacc, tid); __syncthreads();
    level_pass<128, 97, true >(buf[0], buf[1], h0h, h1h, wh[1], wh[0],         lw, yacc, tid);

    // ---- Epilogue: unpack to fp32, GELU, two float4 stores per unit ----
#pragma unroll
    for (int u = 0; u < 3; ++u) {
        const int un = tid + u * BLK;
        if (un >= HALO_U && un < NU) {
            const int p = 8 * un;
            const h8 v = yacc[u];
            float4 oa, ob;
            oa.x = gelu_f((float)v[0]); oa.y = gelu_f((float)v[1]);
            oa.z = gelu_f((float)v[2]); oa.w = gelu_f((float)v[3]);
            ob.x = gelu_f((float)v[4]); ob.y = gelu_f((float)v[5]);
            ob.z = gelu_f((float)v[6]); ob.w = gelu_f((float)v[7]);
            st4f(&out[row + t0 + p], oa);
            st4f(&out[row + t0 + p + 4], ob);
        }
    }
}

}  // namespace

extern "C" void kernel_launch(void* const* d_in, const int* in_sizes, int n_in,
                              void* d_out, int out_size, void* d_ws, size_t ws_size,
                              hipStream_t stream)
{
    const float* x  = (const float*)d_in[0];
    const float* h0 = (const float*)d_in[1];
    const float* h1 = (const float*)d_in[2];
    const float* w  = (const float*)d_in[3];
    float* out = (float*)d_out;

    const int nblocks = (out_size / L_) * NT;   // B*C*NT = 4096
    cmrc_kernel<<<nblocks, BLK, 0, stream>>>(x, h0, h1, w, out);
}

// Round 21
// 40.212 us; speedup vs baseline: 1.7626x; 1.0163x over previous
//
#include <hip/hip_runtime.h>
#include <hip/hip_fp16.h>
#include <cmath>

namespace {

typedef _Float16 h8 __attribute__((ext_vector_type(8)));
typedef _Float16 h2 __attribute__((ext_vector_type(2)));
typedef __fp16   fp2 __attribute__((ext_vector_type(2)));   // cvt_pkrtz native type

constexpr int C_     = 64;
constexpr int L_     = 32768;
constexpr int TILE   = 4096;
constexpr int HALO   = 776;           // receptive field 765, rounded to unit-8
constexpr int NB     = TILE + HALO;   // 4872 halfs
constexpr int NU     = NB / 8;        // 609 h8 units
constexpr int HALO_U = HALO / 8;      // 97
constexpr int NT     = L_ / TILE;     // 8 tiles per row
constexpr int BLK    = 256;
constexpr int S2N    = NU - 2 * BLK;  // 97: threads owning a third unit

__device__ __forceinline__ h8 ld8(const _Float16* p) { return *reinterpret_cast<const h8*>(p); }
__device__ __forceinline__ void st8(_Float16* p, h8 v) { *reinterpret_cast<h8*>(p) = v; }
__device__ __forceinline__ float4 ld4f(const float* p) { return *reinterpret_cast<const float4*>(p); }
__device__ __forceinline__ void st4f(float* p, float4 v) { *reinterpret_cast<float4*>(p) = v; }
__device__ __forceinline__ h8 sp8(_Float16 v) { return (h8){v,v,v,v,v,v,v,v}; }

// Guaranteed v_pk_fma_f16 (r10: measured win vs mul/add trees).
__device__ __forceinline__ h8 fma8(h8 a, h8 b, h8 c) {
    return __builtin_elementwise_fma(a, b, c);
}

template<int K>
__device__ __forceinline__ h8 shconc(h8 A, h8 B) {
    return __builtin_shufflevector(A, B, K, K+1, K+2, K+3, K+4, K+5, K+6, K+7);
}

// f32x8 -> fp16x8 via v_cvt_pkrtz_f16_f32; absmax-verified (r12..r20).
__device__ __forceinline__ h2 pkrtz(float lo, float hi) {
    const fp2 r = __builtin_amdgcn_cvt_pkrtz(lo, hi);
    return __builtin_bit_cast(h2, r);
}
__device__ __forceinline__ h8 pack8(float4 a, float4 b) {
    const h2 p0 = pkrtz(a.x, a.y);
    const h2 p1 = pkrtz(a.z, a.w);
    const h2 p2 = pkrtz(b.x, b.y);
    const h2 p3 = pkrtz(b.z, b.w);
    return (h8){p0[0], p0[1], p1[0], p1[1], p2[0], p2[1], p3[0], p3[1]};
}

// fp16 transcendental helpers (documented HIP half intrinsics -> v_exp_f16 /
// v_rcp_f16).
__device__ __forceinline__ _Float16 exp2_h(_Float16 v) {
    return __builtin_bit_cast(_Float16, hexp2(__builtin_bit_cast(__half, v)));
}
__device__ __forceinline__ _Float16 rcp_h(_Float16 v) {
    return __builtin_bit_cast(_Float16, hrcp(__builtin_bit_cast(__half, v)));
}

// Packed fp16 sigmoid-form GELU: g = y * sigmoid(1.5958*y + 0.07135*y^3),
// computed as 1/(1+exp2(-y*(c1+c2*y^2))) with log2(e)-folded coefficients.
// Saturation exact: y<<0 -> exp2=inf -> rcp=0 -> g=0; y>>0 -> exp2=0 -> g=y.
// Replaces ~72 scalar-fp32 ops/unit with ~29 (3 pk + 8 exp + 8 rcp + 2 pk).
__device__ __forceinline__ h8 gelu8(const h8 y) {
    const h8 y2 = y * y;
    h8 zz = fma8(y2, sp8((_Float16)0.1029535f), sp8((_Float16)2.3022108f));
    zz = zz * y;                         // log2(e)-scaled sigmoid argument
    h8 r;
#pragma unroll
    for (int i = 0; i < 8; ++i) {
        const _Float16 e = exp2_h((_Float16)0.f - zz[i]);
        r[i] = rcp_h((_Float16)1.f + e);
    }
    return y * r;
}

// 4-tap dot helpers (pure pk-FMA chains).
__device__ __forceinline__ h8 dot_nl(const h8 T0, const h8 T1, const h8 T2,
                                     const h8 T3, const _Float16* c) {
    h8 nl = sp8(c[0]) * T0;
    nl = fma8(sp8(c[1]), T1, nl);
    nl = fma8(sp8(c[2]), T2, nl);
    nl = fma8(sp8(c[3]), T3, nl);
    return nl;
}
__device__ __forceinline__ void dot_acc(const h8 T0, const h8 T1, const h8 T2,
                                        const h8 T3, const _Float16* c, h8& yv) {
    h8 yt = yv;
    yt = fma8(sp8(c[0]), T0, yt);
    yt = fma8(sp8(c[1]), T1, yt);
    yt = fma8(sp8(c[2]), T2, yt);
    yt = fma8(sp8(c[3]), T3, yt);
    yv = yt;
}

// Tap gather + two 4-tap dots + in-place publish for one unit of one level.
// D >= 2 only: D=1 is fused into the staging phase (taps from global).
template<int D, bool LAST>
__device__ __forceinline__ void unit_step(const _Float16* __restrict__ src,
                                          _Float16* __restrict__ dst, int un,
                                          h8& lwv, h8& yv, bool doY,
                                          const _Float16* c1, const _Float16* c0)
{
    const int p = 8 * un;
    const h8 T3 = lwv;
    h8 T0, T1, T2;
    if constexpr (D == 2) {
        const h8 Lv = ld8(&src[p - 8]);
        T0 = shconc<2>(Lv, T3); T1 = shconc<4>(Lv, T3); T2 = shconc<6>(Lv, T3);
    } else if constexpr (D == 4) {
        const h8 Lv = ld8(&src[p - 8]);
        const h8 LL = ld8(&src[p - 16]);
        T0 = shconc<4>(LL, Lv); T1 = Lv; T2 = shconc<4>(Lv, T3);
    } else {
        T0 = ld8(&src[p - 3 * D]);
        T1 = ld8(&src[p - 2 * D]);
        T2 = ld8(&src[p - D]);
    }
    if (doY) dot_acc(T0, T1, T2, T3, c1, yv);
    const h8 nl = dot_nl(T0, T1, T2, T3, c0);
    if constexpr (LAST) {
        yv += nl;                      // c0 pre-folded with w0
    } else {
        lwv = nl;
        st8(&dst[p], nl);
    }
}

// One level, dilation D >= 2. Slots compile-time specialized and ordered so
// the UNCONDITIONAL slot1 issues its ds_reads first:
//  slot1 (un=tid+256 in [256,512)): no guard (>=97 always, <NU, y always).
//  slot2 (un=tid+512): exists iff tid<S2N=97; y always.
//  slot0 (un=tid): guard tid>=STARTU; y iff tid>=HALO_U.
// Frontier recursion (correctness-proven r3..r20): STARTU per level
// 2,4,7,13,25,49,97; valid unit g at level D reads down to g-3D/8 >= prev
// STARTU (prev of D2 is the exact fused-staging l1, valid everywhere).
// Guards bound live ranges (r4-r7: unguarded -> 188 VGPR or demotion).
template<int D, int STARTU, bool LAST>
__device__ __forceinline__ void level_pass(const _Float16* __restrict__ src,
                                           _Float16* __restrict__ dst,
                                           const _Float16* h0h, const _Float16* h1h,
                                           _Float16 wih, _Float16 w0h,
                                           h8* lw, h8* yacc, int tid)
{
    _Float16 c1[4], c0[4];
#pragma unroll
    for (int t = 0; t < 4; ++t) {
        c1[t] = wih * h1h[t];
        c0[t] = LAST ? (_Float16)(w0h * h0h[t]) : h0h[t];
    }
    unit_step<D, LAST>(src, dst, tid + BLK, lw[1], yacc[1], true, c1, c0);
    if (tid < S2N)
        unit_step<D, LAST>(src, dst, tid + 2 * BLK, lw[2], yacc[2], true, c1, c0);
    if (tid >= STARTU)
        unit_step<D, LAST>(src, dst, tid, lw[0], yacc[0], tid >= HALO_U, c1, c0);
}

// min-waves=8 (VGPR cap 64): guarded structure measured 32 VGPR (r17/r20).
// LDS 2x9744B -> 8 blocks/CU.
__global__ __launch_bounds__(BLK, 8)
void cmrc_kernel(const float* __restrict__ x,
                 const float* __restrict__ h0,
                 const float* __restrict__ h1,
                 const float* __restrict__ w,
                 float* __restrict__ out)
{
    __shared__ alignas(16) _Float16 buf[2][NB];

    const int tid  = threadIdx.x;
    const int blk  = blockIdx.x;
    const int tile = blk % NT;
    const int bc   = blk / NT;            // b*C + c
    const int c    = bc % C_;
    const long row = (long)bc * L_;
    const int  t0  = tile * TILE - HALO;  // global pos of buffer p=0

    // fp16 filter taps and level weights, converted ONCE.
    _Float16 h0h[4], h1h[4];
#pragma unroll
    for (int k = 0; k < 4; ++k) {
        h0h[k] = (_Float16)h0[c * 4 + k];
        h1h[k] = (_Float16)h1[c * 4 + k];
    }
    _Float16 wh[10];
#pragma unroll
    for (int i = 0; i < 10; ++i) wh[i] = (_Float16)w[c * 10 + i];

    // D=1 y-coefficients for the fused staging phase.
    _Float16 c18[4];
#pragma unroll
    for (int t = 0; t < 4; ++t) c18[t] = wh[8] * h1h[t];

    h8 lw[3];     // running low residual (own units, registers)
    h8 yacc[3];   // packed y accumulator

    // ---- Fused staging + D=1 level (taps from GLOBAL, exact everywhere) ----
    // Loads own 8 x-values plus the 8 preceding halfs (L2-hit neighbor data);
    // computes l1 = conv(x,h0,1) in registers, y = w9*x + w8*conv(x,h1,1),
    // publishes ONLY l1 to LDS. Zero-fill left of t=0 matches the causal pad,
    // so l1 is exact for every unit — no frontier constraint at this level.
#pragma unroll
    for (int u = 0; u < 3; ++u) {
        yacc[u] = sp8((_Float16)0.f);
        const int un = tid + u * BLK;
        if (un < NU) {
            const int p = 8 * un;
            const int t = t0 + p;
            float4 xa = make_float4(0.f, 0.f, 0.f, 0.f), xb = xa;
            float4 xm1 = xa, xm2 = xa;
            if (t >= 0) { xa = ld4f(&x[row + t]);     xb = ld4f(&x[row + t + 4]); }
            if (t >= 8) { xm1 = ld4f(&x[row + t - 8]); xm2 = ld4f(&x[row + t - 4]); }
            const h8 X0 = pack8(xa, xb);
            const h8 Xm = pack8(xm1, xm2);
            const h8 A0 = shconc<5>(Xm, X0);
            const h8 A1 = shconc<6>(Xm, X0);
            const h8 A2 = shconc<7>(Xm, X0);
            const h8 l1 = dot_nl(A0, A1, A2, X0, h0h);
            st8(&buf[0][p], l1);
            lw[u] = l1;
            if (un >= HALO_U) {
                h8 yv = sp8(wh[9]) * X0;
                dot_acc(A0, A1, A2, X0, c18, yv);
                yacc[u] = yv;
            }
        }
    }
    __syncthreads();

    level_pass<2,   2,  false>(buf[0], buf[1], h0h, h1h, wh[7], (_Float16)0.f, lw, yacc, tid); __syncthreads();
    level_pass<4,   4,  false>(buf[1], buf[0], h0h, h1h, wh[6], (_Float16)0.f, lw, yacc, tid); __syncthreads();
    level_pass<8,   7,  false>(buf[0], buf[1], h0h, h1h, wh[5], (_Float16)0.f, lw, yacc, tid); __syncthreads();
    level_pass<16,  13, false>(buf[1], buf[0], h0h, h1h, wh[4], (_Float16)0.f, lw, yacc, tid); __syncthreads();
    level_pass<32,  25, false>(buf[0], buf[1], h0h, h1h, wh[3], (_Float16)0.f, lw, yacc, tid); __syncthreads();
    level_pass<64,  49, false>(buf[1], buf[0], h0h, h1h, wh[2], (_Float16)0.f, lw, yacc, tid); __syncthreads();
    level_pass<128, 97, true >(buf[0], buf[1], h0h, h1h, wh[1], wh[0],         lw, yacc, tid);

    // ---- Epilogue: packed-fp16 GELU, unpack to fp32, two float4 stores ----
#pragma unroll
    for (int u = 0; u < 3; ++u) {
        const int un = tid + u * BLK;
        if (un >= HALO_U && un < NU) {
            const int p = 8 * un;
            const h8 g = gelu8(yacc[u]);
            float4 oa, ob;
            oa.x = (float)g[0]; oa.y = (float)g[1];
            oa.z = (float)g[2]; oa.w = (float)g[3];
            ob.x = (float)g[4]; ob.y = (float)g[5];
            ob.z = (float)g[6]; ob.w = (float)g[7];
            st4f(&out[row + t0 + p], oa);
            st4f(&out[row + t0 + p + 4], ob);
        }
    }
}

}  // namespace

extern "C" void kernel_launch(void* const* d_in, const int* in_sizes, int n_in,
                              void* d_out, int out_size, void* d_ws, size_t ws_size,
                              hipStream_t stream)
{
    const float* x  = (const float*)d_in[0];
    const float* h0 = (const float*)d_in[1];
    const float* h1 = (const float*)d_in[2];
    const float* w  = (const float*)d_in[3];
    float* out = (float*)d_out;

    const int nblocks = (out_size / L_) * NT;   // B*C*NT = 4096
    cmrc_kernel<<<nblocks, BLK, 0, stream>>>(x, h0, h1, w, out);
}